// Round 25
// baseline (169.177 us; speedup 1.0000x reference)
//
#include <hip/hip_runtime.h>
#include <cstdint>

// ---- problem constants ----
// B=8, T=1024, E=128, H=1024, NH=16, HD=64, S=T+E=1152
// inputs fp32; compute in bf16 MFMA with fp32 accum.

typedef __attribute__((ext_vector_type(8))) short s16x8;   // 8 bf16 (4 VGPR) MFMA operand
typedef __attribute__((ext_vector_type(4))) float f32x4;   // MFMA accumulator
typedef __attribute__((ext_vector_type(4))) unsigned short u16x4;
typedef __attribute__((ext_vector_type(4))) unsigned int u32x4;

#define DEVFN static __device__ __forceinline__

DEVFN unsigned short f2bf(float f) {  // RNE float->bf16
  uint32_t u = __builtin_bit_cast(uint32_t, f);
  u += 0x7fffu + ((u >> 16) & 1u);
  return (unsigned short)(u >> 16);
}

DEVFN uint32_t pk_bf16(float lo, float hi) {  // HW RNE pack (proven r2/r6/r7/r16/r17/r23)
  uint32_t r;
  asm("v_cvt_pk_bf16_f32 %0, %1, %2" : "=v"(r) : "v"(lo), "v"(hi));
  return r;
}

DEVFN float vexp2(float x) {  // native 2^x: single v_exp_f32 (proven r17)
  float r;
  asm("v_exp_f32 %0, %1" : "=v"(r) : "v"(x));
  return r;
}

DEVFN void gload16(const void* g, void* lds) {  // async global->LDS, 16B/lane
  using GP = const __attribute__((address_space(1))) uint32_t*;
  using LP = __attribute__((address_space(3))) uint32_t*;
  __builtin_amdgcn_global_load_lds(
      reinterpret_cast<GP>(reinterpret_cast<uintptr_t>(g)),
      reinterpret_cast<LP>((uint32_t)reinterpret_cast<uintptr_t>(lds)),
      16, 0, 0);
}

// ---------------- prep: fp32 -> bf16 casts (+ pos_ent fuse) ----------------
// ws bf16 layout (elements):
//   tokBF  @ 0        : 8388608   (tok [8192][1024])
//   peBF   @ 8388608  : 1048576   ((ent+qpos)*0.5 [1024][1024])
//   entBF  @ 9437184  : 1048576
//   WBF    @ 10485760 : 6*1048576 (row-major [n][k] = B^T layout)
//   Qb     @ 16777216 : 9437184   ([bh][s][64], pre-scaled by 0.125*log2e)
//   Kb     @ 26214400 : 9437184   ([bh][s][64])
//   Vtb    @ 35651584 : 9437184   ([bh][64][s] transposed for PV)
__global__ __launch_bounds__(256) void prep_kernel(
    const float* __restrict__ tok, const float* __restrict__ ent,
    const float* __restrict__ qpos,
    const float* __restrict__ W0, const float* __restrict__ W1,
    const float* __restrict__ W2, const float* __restrict__ W3,
    const float* __restrict__ W4, const float* __restrict__ W5,
    unsigned short* __restrict__ dst)
{
  const int NG = 4194304;
  for (int g = blockIdx.x * blockDim.x + threadIdx.x; g < NG;
       g += gridDim.x * blockDim.x) {
    int e = g << 2;
    f32x4 v;
    if (e < 8388608) {
      v = *(const f32x4*)(tok + e);
    } else if (e < 9437184) {
      int i = e - 8388608;
      f32x4 a = *(const f32x4*)(ent + i);
      f32x4 p = *(const f32x4*)(qpos + i);
      v = (a + p) * 0.5f;
    } else if (e < 10485760) {
      v = *(const f32x4*)(ent + (e - 9437184));
    } else {
      int i = e - 10485760;
      int wsel = i >> 20;
      const float* W = wsel == 0 ? W0 : wsel == 1 ? W1 : wsel == 2 ? W2
                     : wsel == 3 ? W3 : wsel == 4 ? W4 : W5;
      v = *(const f32x4*)(W + (i & 1048575));
    }
    u16x4 o;
#pragma unroll
    for (int j = 0; j < 4; ++j) o[j] = f2bf(v[j]);
    *(u16x4*)(dst + e) = o;
  }
}

// ---------------- projection GEMM: 256x128 tile, 8 waves, counted-vmcnt ----
// vs round-24 PASSING proj, ONE lever: tile 128x128 -> 256x128 with 8 waves
// (512 threads). Grid 1728 -> 864 blocks (dispatch tail 1.35 -> 1.125
// rounds); staging bytes/FLOP 15.2 -> 11.4 KB/MFLOP (B shared by 2x M-rows);
// 3 blocks/CU x 8 waves = 24 waves/CU static. Same per-wave register cost
// (acc[4][4]), same chunk swizzle / fragment-offset / counted-vmcnt formulas
// with re-derived constants: stage = 3 loads (2 A-chunks + 1 B-chunk),
// 2-deep -> vmcnt(3) at iter entry, peel at vmcnt(0).
__global__ __launch_bounds__(512) void proj_gemm(
    const unsigned short* __restrict__ Atok, const unsigned short* __restrict__ Ape,
    const unsigned short* __restrict__ Aent, const unsigned short* __restrict__ Wb6,
    const float* __restrict__ b0, const float* __restrict__ b1,
    const float* __restrict__ b2, const float* __restrict__ b3,
    const float* __restrict__ b4, const float* __restrict__ b5,
    unsigned short* __restrict__ Qo, unsigned short* __restrict__ Ko,
    unsigned short* __restrict__ Vt)
{
  __shared__ __align__(16) unsigned short As[2][8192];  // [buf][256x32]
  __shared__ __align__(16) unsigned short Bs[2][4096];  // [buf][128x32]

  const int tid = threadIdx.x;
  const int l = tid & 63, w = tid >> 6;          // w 0..7
  const int lr = l & 15, lg = l >> 4;
  const int bx = blockIdx.x, by = blockIdx.y;    // bx 0..23, by 0..35
  const int which = bx >> 3;            // 0=Q 1=K 2=V
  const int n0l = (bx & 7) << 7;
  const bool entm = by >= 32;
  const int byl = entm ? by - 32 : by;  // 256-row tile index
  const int wsel = which + (entm ? 3 : 0);
  const unsigned short* A = entm ? (which == 2 ? Aent : Ape) : Atok;
  const unsigned short* Wp = Wb6 + (size_t)wsel * 1048576;
  const float* bias = entm ? (which == 0 ? b3 : which == 1 ? b4 : b5)
                           : (which == 0 ? b0 : which == 1 ? b1 : b2);
  const int bShift = entm ? 7 : 10;
  const int sBase = entm ? 1024 : 0;
  // fold 1/sqrt(HD) AND log2(e) into Q so attention can use exp2 directly
  const float qscale = (which == 0) ? 0.125f * 1.44269504088896f : 1.0f;

  // staging: A = 16 chunks of 1KB (wave w stages 2w, 2w+1); B = 8 (wave w: w)
  const int c0 = w * 2, c1 = w * 2 + 1;
  const int srA0 = c0 * 16 + (l >> 2), srA1 = c1 * 16 + (l >> 2);
  const int srB  = w * 16 + (l >> 2);
  const int scA0 = ((l & 3) * 8) ^ (((srA0 >> 1) & 3) << 3);
  const int scA1 = ((l & 3) * 8) ^ (((srA1 >> 1) & 3) << 3);
  const int scB  = ((l & 3) * 8) ^ (((srB  >> 1) & 3) << 3);
  const unsigned short* gA0 = A + (size_t)(byl * 256 + srA0) * 1024 + scA0;
  const unsigned short* gA1 = A + (size_t)(byl * 256 + srA1) * 1024 + scA1;
  const unsigned short* gB0 = Wp + (size_t)(n0l + srB) * 1024 + scB;

  const int wr = w >> 1, wc = w & 1;   // wr 0..3 (64-row quads), wc 0..1
  int offA[4], offB[4];
#pragma unroll
  for (int mi = 0; mi < 4; ++mi) {
    int row = wr * 64 + mi * 16 + lr;            // 0..255
    offA[mi] = row * 32 + ((lg * 8) ^ (((row >> 1) & 3) << 3));
  }
#pragma unroll
  for (int ni = 0; ni < 4; ++ni) {
    int row = wc * 64 + ni * 16 + lr;            // 0..127
    offB[ni] = row * 32 + ((lg * 8) ^ (((row >> 1) & 3) << 3));
  }

  auto STAGE = [&](int kt, int bi) {   // 3 gload_lds per wave
    const int ko = kt * 32;
    gload16(gA0 + ko, &As[bi][c0 * 512]);
    gload16(gA1 + ko, &As[bi][c1 * 512]);
    gload16(gB0 + ko, &Bs[bi][w * 512]);
  };

  auto COMPUTE = [&](int cur, f32x4 (&acc)[4][4]) {
    s16x8 a[4], b[4];
#pragma unroll
    for (int mi = 0; mi < 4; ++mi) a[mi] = *(const s16x8*)(&As[cur][offA[mi]]);
#pragma unroll
    for (int ni = 0; ni < 4; ++ni) b[ni] = *(const s16x8*)(&Bs[cur][offB[ni]]);
#pragma unroll
    for (int mi = 0; mi < 4; ++mi)
#pragma unroll
      for (int ni = 0; ni < 4; ++ni)
        acc[mi][ni] = __builtin_amdgcn_mfma_f32_16x16x32_bf16(
            a[mi], b[ni], acc[mi][ni], 0, 0, 0);
  };

  f32x4 acc[4][4] = {};
  STAGE(0, 0);
  STAGE(1, 1);
  for (int kt = 0; kt < 31; ++kt) {
    const int cur = kt & 1;
    asm volatile("s_waitcnt vmcnt(3)" ::: "memory");  // STAGE(kt) landed;
    __builtin_amdgcn_s_barrier();                     // STAGE(kt+1) in flight
    COMPUTE(cur, acc);
    __builtin_amdgcn_s_barrier();                     // buf[cur] free
    if (kt + 2 < 32) STAGE(kt + 2, cur);
  }
  {  // peeled last iteration: nothing newer in flight -> full drain
    asm volatile("s_waitcnt vmcnt(0)" ::: "memory");
    __builtin_amdgcn_s_barrier();
    COMPUTE(31 & 1, acc);
  }

  const int bMask = (1 << bShift) - 1;
#pragma unroll
  for (int mi = 0; mi < 4; ++mi) {
    const int i0 = byl * 256 + wr * 64 + mi * 16 + lg * 4;
#pragma unroll
    for (int ni = 0; ni < 4; ++ni) {
      const int j = n0l + wc * 64 + ni * 16 + lr;
      const float bv = bias[j];
      const int h = j >> 6, d = j & 63;
      if (which < 2) {
        unsigned short* dst = (which == 0) ? Qo : Ko;
#pragma unroll
        for (int r = 0; r < 4; ++r) {
          const int i = i0 + r;
          const int bidx = i >> bShift;
          const int s = sBase + (i & bMask);
          dst[((size_t)(bidx * 16 + h) * 1152 + s) * 64 + d] =
              f2bf((acc[mi][ni][r] + bv) * qscale);
        }
      } else {
        const int bidx = i0 >> bShift;
        const int s0 = sBase + (i0 & bMask);
        u16x4 pk;
#pragma unroll
        for (int r = 0; r < 4; ++r) pk[r] = f2bf(acc[mi][ni][r] + bv);
        *(u16x4*)(Vt + ((size_t)(bidx * 16 + h) * 64 + d) * 1152 + s0) = pk;
      }
    }
  }
}

// ---------------- flash attention (byte-identical to round-23/24 PASSING) --
__global__ __launch_bounds__(256) void attn_kernel(
    const unsigned short* __restrict__ Q, const unsigned short* __restrict__ K,
    const unsigned short* __restrict__ Vt, const float* __restrict__ mask,
    float* __restrict__ out)
{
  __shared__ __align__(16) unsigned short Klds[2][4096];  // [64 kv][64 d] swz
  __shared__ __align__(16) unsigned short Vlds[2][4096];  // [64 d][64 kv] swz
  const int tid = threadIdx.x, l = tid & 63, w = tid >> 6;
  const int c = l & 15, g = l >> 4;
  const int nblk = blockIdx.x;
  const int xcd = nblk & 7, jj = nblk >> 3;   // jj 0..143
  const int qt = jj % 9;
  const int bh = (jj / 9) * 8 + xcd;
  const int b = bh >> 4, h = bh & 15;
  const unsigned short* Qh = Q + (size_t)bh * 73728;
  const unsigned short* Kh = K + (size_t)bh * 73728;
  const unsigned short* Vh = Vt + (size_t)bh * 73728;  // [64][1152]
  const float* mrow = mask + b * 1152;
  const int q0 = qt * 128 + w * 32;
  const f32x4 fz = {0.f, 0.f, 0.f, 0.f};
  const float LOG2E = 1.44269504088896f;

  // staging lane constants: wave w owns 1KB chunks {2w, 2w+1} of each tile.
  const int rsub = l >> 3;
  const int ksw8 = ((l & 7) ^ rsub) << 3;          // source elem offset
  const int ccA = w * 2, ccB = w * 2 + 1;
  const int rA = ccA * 8 + rsub, rB = ccB * 8 + rsub;
  // read-side swizzled 16B-slot offsets for row with row&7 == c&7:
  const int q1 = (g ^ (c & 7)) << 3;
  const int q2 = ((g + 4) ^ (c & 7)) << 3;

  // all-ones bf16 A-fragment for the denominator MFMA
  s16x8 ones;
#pragma unroll
  for (int j = 0; j < 8; ++j) ones[j] = (short)0x3F80;

  // Q as B-operand: lane holds Q[q0+mi*16+c][ds*32 + g*8 + j]
  s16x8 qb[2][2];
#pragma unroll
  for (int mi = 0; mi < 2; ++mi)
#pragma unroll
    for (int ds = 0; ds < 2; ++ds)
      qb[mi][ds] =
          *(const s16x8*)(Qh + (size_t)(q0 + mi * 16 + c) * 64 + ds * 32 + g * 8);

  f32x4 OT[2][4] = {};              // O^T[d=di*16+g*4+r][q=mi*16+c]
  f32x4 den[2] = {};                // Sum(p) per mi (all 4 comps equal)

  auto STAGE = [&](int tt, int bi) {
    const int kv0 = tt * 64;
    gload16(Kh + (size_t)(kv0 + rA) * 64 + ksw8, &Klds[bi][ccA * 512]);
    gload16(Kh + (size_t)(kv0 + rB) * 64 + ksw8, &Klds[bi][ccB * 512]);
    gload16(Vh + (size_t)rA * 1152 + kv0 + ksw8, &Vlds[bi][ccA * 512]);
    gload16(Vh + (size_t)rB * 1152 + kv0 + ksw8, &Vlds[bi][ccB * 512]);
  };

  STAGE(0, 0);
  for (int t = 0; t < 18; ++t) {
    const int kv0 = t * 64;
    const int cur = t & 1;
    __syncthreads();   // vmcnt(0) drain: stage(t) visible; prior reads done

    // mask loads first (their vmcnt wait then doesn't drain the new stage)
    f32x4 mv[4];
#pragma unroll
    for (int ni = 0; ni < 4; ++ni)
      mv[ni] = *(const f32x4*)(mrow + kv0 + ni * 16 + g * 4) * LOG2E;

    if (t + 1 < 18) STAGE(t + 1, cur ^ 1);   // overlaps compute below

    // ---- S' = (K Q^T + mask)*log2e  (scales folded; K from LDS) ----
    f32x4 st[2][4];
#pragma unroll
    for (int ni = 0; ni < 4; ++ni) {
      const unsigned short* kp = &Klds[cur][(ni * 16 + c) * 64];
      s16x8 ka0 = *(const s16x8*)(kp + q1);
      s16x8 ka1 = *(const s16x8*)(kp + q2);
#pragma unroll
      for (int mi = 0; mi < 2; ++mi) {
        f32x4 tq = __builtin_amdgcn_mfma_f32_16x16x32_bf16(ka0, qb[mi][0], fz, 0, 0, 0);
        tq = __builtin_amdgcn_mfma_f32_16x16x32_bf16(ka1, qb[mi][1], tq, 0, 0, 0);
        st[mi][ni] = tq + mv[ni];
      }
    }

    // ---- p = 2^s': raw v_exp_f32, no cross-lane ops ----
#pragma unroll
    for (int mi = 0; mi < 2; ++mi)
#pragma unroll
      for (int ni = 0; ni < 4; ++ni)
#pragma unroll
        for (int r = 0; r < 4; ++r)
          st[mi][ni][r] = vexp2(st[mi][ni][r]);

    // ---- build P^T B-fragments in-register: cvt_pk + permlane swaps ----
    s16x8 pb[2][2];
#pragma unroll
    for (int mi = 0; mi < 2; ++mi)
#pragma unroll
      for (int ks = 0; ks < 2; ++ks) {
        uint32_t x  = pk_bf16(st[mi][2 * ks][0],     st[mi][2 * ks][1]);
        uint32_t y  = pk_bf16(st[mi][2 * ks + 1][0], st[mi][2 * ks + 1][1]);
        uint32_t x2 = pk_bf16(st[mi][2 * ks][2],     st[mi][2 * ks][3]);
        uint32_t y2 = pk_bf16(st[mi][2 * ks + 1][2], st[mi][2 * ks + 1][3]);
        asm("v_permlane32_swap_b32 %0, %1" : "+v"(x), "+v"(y));
        asm("v_permlane16_swap_b32 %0, %1" : "+v"(x), "+v"(y));   // x=dw0 y=dw2
        asm("v_permlane32_swap_b32 %0, %1" : "+v"(x2), "+v"(y2));
        asm("v_permlane16_swap_b32 %0, %1" : "+v"(x2), "+v"(y2)); // x2=dw1 y2=dw3
        u32x4 dw = {x, x2, y, y2};
        pb[mi][ks] = __builtin_bit_cast(s16x8, dw);
      }

    // ---- O^T += V^T P^T ; den += ones . P^T  (V from LDS) ----
#pragma unroll
    for (int di = 0; di < 4; ++di) {
      const unsigned short* vp = &Vlds[cur][(di * 16 + c) * 64];
      s16x8 va0 = *(const s16x8*)(vp + q1);
      s16x8 va1 = *(const s16x8*)(vp + q2);
#pragma unroll
      for (int mi = 0; mi < 2; ++mi) {
        OT[mi][di] =
            __builtin_amdgcn_mfma_f32_16x16x32_bf16(va0, pb[mi][0], OT[mi][di], 0, 0, 0);
        OT[mi][di] =
            __builtin_amdgcn_mfma_f32_16x16x32_bf16(va1, pb[mi][1], OT[mi][di], 0, 0, 0);
      }
    }
#pragma unroll
    for (int mi = 0; mi < 2; ++mi) {
      den[mi] = __builtin_amdgcn_mfma_f32_16x16x32_bf16(ones, pb[mi][0], den[mi], 0, 0, 0);
      den[mi] = __builtin_amdgcn_mfma_f32_16x16x32_bf16(ones, pb[mi][1], den[mi], 0, 0, 0);
    }
  }

  // ---- normalize + direct store (block-uniform tok/ent region) ----
  float* obase;
  if (q0 < 1024) {
    obase = out + ((size_t)(b * 1024 + q0) * 1024 + h * 64);
  } else {
    obase = out + 8388608u + ((size_t)(b * 128 + (q0 - 1024)) * 1024 + h * 64);
  }
  float inv[2] = {1.0f / den[0][0], 1.0f / den[1][0]};
#pragma unroll
  for (int mi = 0; mi < 2; ++mi)
#pragma unroll
    for (int di = 0; di < 4; ++di) {
      f32x4 v = OT[mi][di] * inv[mi];
      *(f32x4*)(obase + (size_t)(mi * 16 + c) * 1024 + di * 16 + g * 4) = v;
    }
}

// ---------------- launch ----------------
extern "C" void kernel_launch(void* const* d_in, const int* in_sizes, int n_in,
                              void* d_out, int out_size, void* d_ws, size_t ws_size,
                              hipStream_t stream) {
  const float* tok  = (const float*)d_in[0];
  const float* ent  = (const float*)d_in[1];
  const float* mask = (const float*)d_in[2];
  const float* qpos = (const float*)d_in[3];
  const float* Wq  = (const float*)d_in[4];  const float* bq  = (const float*)d_in[5];
  const float* Wk  = (const float*)d_in[6];  const float* bk  = (const float*)d_in[7];
  const float* Wv  = (const float*)d_in[8];  const float* bv  = (const float*)d_in[9];
  const float* Weq = (const float*)d_in[10]; const float* beq = (const float*)d_in[11];
  const float* Wek = (const float*)d_in[12]; const float* bek = (const float*)d_in[13];
  const float* Wev = (const float*)d_in[14]; const float* bev = (const float*)d_in[15];
  float* out = (float*)d_out;

  unsigned short* ws = (unsigned short*)d_ws;
  unsigned short* tokBF = ws;
  unsigned short* peBF  = ws + 8388608;
  unsigned short* entBF = ws + 9437184;
  unsigned short* WBF   = ws + 10485760;
  unsigned short* Qb    = ws + 16777216;
  unsigned short* Kb    = ws + 26214400;
  unsigned short* Vtb   = ws + 35651584;

  prep_kernel<<<2048, 256, 0, stream>>>(tok, ent, qpos, Wq, Wk, Wv, Weq, Wek, Wev, ws);
  proj_gemm<<<dim3(24, 36), 512, 0, stream>>>(tokBF, peBF, entBF, WBF,
                                              bq, bk, bv, beq, bek, bev,
                                              Qb, Kb, Vtb);
  attn_kernel<<<1152, 256, 0, stream>>>(Qb, Kb, Vtb, mask, out);
}

// Round 26
// 159.465 us; speedup vs baseline: 1.0609x; 1.0609x over previous
//
#include <hip/hip_runtime.h>
#include <cstdint>

// ---- problem constants ----
// B=8, T=1024, E=128, H=1024, NH=16, HD=64, S=T+E=1152
// inputs fp32; compute in bf16 MFMA with fp32 accum.
// FINAL (round 26) = round-24 configuration, the session best (159.5 us):
//   prep: vectorized fp32->bf16 casts (+pos_ent fuse)
//   proj: 128x128 tile, BK=32, counted-vmcnt 2-deep pipeline (R20+R24)
//   attn: no-max softmax, MFMA denominator, in-register P^T (R23),
//         double-buffered K/V LDS staging (R13), XCD-bijective grid (R6)

typedef __attribute__((ext_vector_type(8))) short s16x8;   // 8 bf16 (4 VGPR) MFMA operand
typedef __attribute__((ext_vector_type(4))) float f32x4;   // MFMA accumulator
typedef __attribute__((ext_vector_type(4))) unsigned short u16x4;
typedef __attribute__((ext_vector_type(4))) unsigned int u32x4;

#define DEVFN static __device__ __forceinline__

DEVFN unsigned short f2bf(float f) {  // RNE float->bf16
  uint32_t u = __builtin_bit_cast(uint32_t, f);
  u += 0x7fffu + ((u >> 16) & 1u);
  return (unsigned short)(u >> 16);
}

DEVFN uint32_t pk_bf16(float lo, float hi) {  // HW RNE pack (proven r2/r6/r7/r16/r17/r23)
  uint32_t r;
  asm("v_cvt_pk_bf16_f32 %0, %1, %2" : "=v"(r) : "v"(lo), "v"(hi));
  return r;
}

DEVFN float vexp2(float x) {  // native 2^x: single v_exp_f32 (proven r17)
  float r;
  asm("v_exp_f32 %0, %1" : "=v"(r) : "v"(x));
  return r;
}

DEVFN void gload16(const void* g, void* lds) {  // async global->LDS, 16B/lane
  using GP = const __attribute__((address_space(1))) uint32_t*;
  using LP = __attribute__((address_space(3))) uint32_t*;
  __builtin_amdgcn_global_load_lds(
      reinterpret_cast<GP>(reinterpret_cast<uintptr_t>(g)),
      reinterpret_cast<LP>((uint32_t)reinterpret_cast<uintptr_t>(lds)),
      16, 0, 0);
}

// ---------------- prep: fp32 -> bf16 casts (+ pos_ent fuse) ----------------
// ws bf16 layout (elements):
//   tokBF  @ 0        : 8388608   (tok [8192][1024])
//   peBF   @ 8388608  : 1048576   ((ent+qpos)*0.5 [1024][1024])
//   entBF  @ 9437184  : 1048576
//   WBF    @ 10485760 : 6*1048576 (row-major [n][k] = B^T layout)
//   Qb     @ 16777216 : 9437184   ([bh][s][64], pre-scaled by 0.125*log2e)
//   Kb     @ 26214400 : 9437184   ([bh][s][64])
//   Vtb    @ 35651584 : 9437184   ([bh][64][s] transposed for PV)
__global__ __launch_bounds__(256) void prep_kernel(
    const float* __restrict__ tok, const float* __restrict__ ent,
    const float* __restrict__ qpos,
    const float* __restrict__ W0, const float* __restrict__ W1,
    const float* __restrict__ W2, const float* __restrict__ W3,
    const float* __restrict__ W4, const float* __restrict__ W5,
    unsigned short* __restrict__ dst)
{
  const int NG = 4194304;
  for (int g = blockIdx.x * blockDim.x + threadIdx.x; g < NG;
       g += gridDim.x * blockDim.x) {
    int e = g << 2;
    f32x4 v;
    if (e < 8388608) {
      v = *(const f32x4*)(tok + e);
    } else if (e < 9437184) {
      int i = e - 8388608;
      f32x4 a = *(const f32x4*)(ent + i);
      f32x4 p = *(const f32x4*)(qpos + i);
      v = (a + p) * 0.5f;
    } else if (e < 10485760) {
      v = *(const f32x4*)(ent + (e - 9437184));
    } else {
      int i = e - 10485760;
      int wsel = i >> 20;
      const float* W = wsel == 0 ? W0 : wsel == 1 ? W1 : wsel == 2 ? W2
                     : wsel == 3 ? W3 : wsel == 4 ? W4 : W5;
      v = *(const f32x4*)(W + (i & 1048575));
    }
    u16x4 o;
#pragma unroll
    for (int j = 0; j < 4; ++j) o[j] = f2bf(v[j]);
    *(u16x4*)(dst + e) = o;
  }
}

// ---------------- projection GEMM: BK=32 + counted-vmcnt pipeline ----------
// (round-24 PASSING form: 128x128 tile, 4 waves, 32KB LDS -> ~5 blocks/CU;
//  2-deep stage prologue; per iter: vmcnt(4) [STAGE(kt) landed, STAGE(kt+1)
//  in flight] -> raw barrier -> compute -> barrier -> STAGE(kt+2);
//  last iter peeled at vmcnt(0). No setprio.)
__global__ __launch_bounds__(256) void proj_gemm(
    const unsigned short* __restrict__ Atok, const unsigned short* __restrict__ Ape,
    const unsigned short* __restrict__ Aent, const unsigned short* __restrict__ Wb6,
    const float* __restrict__ b0, const float* __restrict__ b1,
    const float* __restrict__ b2, const float* __restrict__ b3,
    const float* __restrict__ b4, const float* __restrict__ b5,
    unsigned short* __restrict__ Qo, unsigned short* __restrict__ Ko,
    unsigned short* __restrict__ Vt)
{
  __shared__ __align__(16) unsigned short As[2][4096];  // [buf][128x32]
  __shared__ __align__(16) unsigned short Bs[2][4096];

  const int tid = threadIdx.x;
  const int l = tid & 63, w = tid >> 6;
  const int lr = l & 15, lg = l >> 4;
  const int bx = blockIdx.x, by = blockIdx.y;
  const int which = bx >> 3;            // 0=Q 1=K 2=V
  const int n0l = (bx & 7) << 7;
  const bool entm = by >= 64;
  const int byl = entm ? by - 64 : by;
  const int wsel = which + (entm ? 3 : 0);
  const unsigned short* A = entm ? (which == 2 ? Aent : Ape) : Atok;
  const unsigned short* Wp = Wb6 + (size_t)wsel * 1048576;
  const float* bias = entm ? (which == 0 ? b3 : which == 1 ? b4 : b5)
                           : (which == 0 ? b0 : which == 1 ? b1 : b2);
  const int bShift = entm ? 7 : 10;
  const int sBase = entm ? 1024 : 0;
  // fold 1/sqrt(HD) AND log2(e) into Q so attention can use exp2 directly
  const float qscale = (which == 0) ? 0.125f * 1.44269504088896f : 1.0f;

  const int c0 = w * 2, c1 = w * 2 + 1;
  const int sr0 = c0 * 16 + (l >> 2), sr1 = c1 * 16 + (l >> 2);
  const int sc0 = ((l & 3) * 8) ^ (((sr0 >> 1) & 3) << 3);
  const int sc1 = ((l & 3) * 8) ^ (((sr1 >> 1) & 3) << 3);
  const unsigned short* gA0 = A + (size_t)(byl * 128 + sr0) * 1024 + sc0;
  const unsigned short* gA1 = A + (size_t)(byl * 128 + sr1) * 1024 + sc1;
  const unsigned short* gB0 = Wp + (size_t)(n0l + sr0) * 1024 + sc0;
  const unsigned short* gB1 = Wp + (size_t)(n0l + sr1) * 1024 + sc1;

  const int wr = w >> 1, wc = w & 1;
  int offA[4], offB[4];
#pragma unroll
  for (int mi = 0; mi < 4; ++mi) {
    int row = wr * 64 + mi * 16 + lr;
    offA[mi] = row * 32 + ((lg * 8) ^ (((row >> 1) & 3) << 3));
  }
#pragma unroll
  for (int ni = 0; ni < 4; ++ni) {
    int row = wc * 64 + ni * 16 + lr;
    offB[ni] = row * 32 + ((lg * 8) ^ (((row >> 1) & 3) << 3));
  }

  auto STAGE = [&](int kt, int bi) {   // 4 gload_lds per wave
    const int ko = kt * 32;
    gload16(gA0 + ko, &As[bi][c0 * 512]);
    gload16(gA1 + ko, &As[bi][c1 * 512]);
    gload16(gB0 + ko, &Bs[bi][c0 * 512]);
    gload16(gB1 + ko, &Bs[bi][c1 * 512]);
  };

  auto COMPUTE = [&](int cur, f32x4 (&acc)[4][4]) {
    s16x8 a[4], b[4];
#pragma unroll
    for (int mi = 0; mi < 4; ++mi) a[mi] = *(const s16x8*)(&As[cur][offA[mi]]);
#pragma unroll
    for (int ni = 0; ni < 4; ++ni) b[ni] = *(const s16x8*)(&Bs[cur][offB[ni]]);
#pragma unroll
    for (int mi = 0; mi < 4; ++mi)
#pragma unroll
      for (int ni = 0; ni < 4; ++ni)
        acc[mi][ni] = __builtin_amdgcn_mfma_f32_16x16x32_bf16(
            a[mi], b[ni], acc[mi][ni], 0, 0, 0);
  };

  f32x4 acc[4][4] = {};
  STAGE(0, 0);
  STAGE(1, 1);
  for (int kt = 0; kt < 31; ++kt) {
    const int cur = kt & 1;
    asm volatile("s_waitcnt vmcnt(4)" ::: "memory");  // STAGE(kt) landed;
    __builtin_amdgcn_s_barrier();                     // STAGE(kt+1) in flight
    COMPUTE(cur, acc);
    __builtin_amdgcn_s_barrier();                     // buf[cur] free
    if (kt + 2 < 32) STAGE(kt + 2, cur);
  }
  {  // peeled last iteration: nothing newer in flight -> full drain
    asm volatile("s_waitcnt vmcnt(0)" ::: "memory");
    __builtin_amdgcn_s_barrier();
    COMPUTE(31 & 1, acc);
  }

  const int bMask = (1 << bShift) - 1;
#pragma unroll
  for (int mi = 0; mi < 4; ++mi) {
    const int i0 = byl * 128 + wr * 64 + mi * 16 + lg * 4;
#pragma unroll
    for (int ni = 0; ni < 4; ++ni) {
      const int j = n0l + wc * 64 + ni * 16 + lr;
      const float bv = bias[j];
      const int h = j >> 6, d = j & 63;
      if (which < 2) {
        unsigned short* dst = (which == 0) ? Qo : Ko;
#pragma unroll
        for (int r = 0; r < 4; ++r) {
          const int i = i0 + r;
          const int bidx = i >> bShift;
          const int s = sBase + (i & bMask);
          dst[((size_t)(bidx * 16 + h) * 1152 + s) * 64 + d] =
              f2bf((acc[mi][ni][r] + bv) * qscale);
        }
      } else {
        const int bidx = i0 >> bShift;
        const int s0 = sBase + (i0 & bMask);
        u16x4 pk;
#pragma unroll
        for (int r = 0; r < 4; ++r) pk[r] = f2bf(acc[mi][ni][r] + bv);
        *(u16x4*)(Vt + ((size_t)(bidx * 16 + h) * 64 + d) * 1152 + s0) = pk;
      }
    }
  }
}

// ---------------- flash attention (round-23/24 PASSING form) ---------------
__global__ __launch_bounds__(256) void attn_kernel(
    const unsigned short* __restrict__ Q, const unsigned short* __restrict__ K,
    const unsigned short* __restrict__ Vt, const float* __restrict__ mask,
    float* __restrict__ out)
{
  __shared__ __align__(16) unsigned short Klds[2][4096];  // [64 kv][64 d] swz
  __shared__ __align__(16) unsigned short Vlds[2][4096];  // [64 d][64 kv] swz
  const int tid = threadIdx.x, l = tid & 63, w = tid >> 6;
  const int c = l & 15, g = l >> 4;
  const int nblk = blockIdx.x;
  const int xcd = nblk & 7, jj = nblk >> 3;   // jj 0..143
  const int qt = jj % 9;
  const int bh = (jj / 9) * 8 + xcd;
  const int b = bh >> 4, h = bh & 15;
  const unsigned short* Qh = Q + (size_t)bh * 73728;
  const unsigned short* Kh = K + (size_t)bh * 73728;
  const unsigned short* Vh = Vt + (size_t)bh * 73728;  // [64][1152]
  const float* mrow = mask + b * 1152;
  const int q0 = qt * 128 + w * 32;
  const f32x4 fz = {0.f, 0.f, 0.f, 0.f};
  const float LOG2E = 1.44269504088896f;

  // staging lane constants: wave w owns 1KB chunks {2w, 2w+1} of each tile.
  const int rsub = l >> 3;
  const int ksw8 = ((l & 7) ^ rsub) << 3;          // source elem offset
  const int ccA = w * 2, ccB = w * 2 + 1;
  const int rA = ccA * 8 + rsub, rB = ccB * 8 + rsub;
  // read-side swizzled 16B-slot offsets for row with row&7 == c&7:
  const int q1 = (g ^ (c & 7)) << 3;
  const int q2 = ((g + 4) ^ (c & 7)) << 3;

  // all-ones bf16 A-fragment for the denominator MFMA
  s16x8 ones;
#pragma unroll
  for (int j = 0; j < 8; ++j) ones[j] = (short)0x3F80;

  // Q as B-operand: lane holds Q[q0+mi*16+c][ds*32 + g*8 + j]
  s16x8 qb[2][2];
#pragma unroll
  for (int mi = 0; mi < 2; ++mi)
#pragma unroll
    for (int ds = 0; ds < 2; ++ds)
      qb[mi][ds] =
          *(const s16x8*)(Qh + (size_t)(q0 + mi * 16 + c) * 64 + ds * 32 + g * 8);

  f32x4 OT[2][4] = {};              // O^T[d=di*16+g*4+r][q=mi*16+c]
  f32x4 den[2] = {};                // Sum(p) per mi (all 4 comps equal)

  auto STAGE = [&](int tt, int bi) {
    const int kv0 = tt * 64;
    gload16(Kh + (size_t)(kv0 + rA) * 64 + ksw8, &Klds[bi][ccA * 512]);
    gload16(Kh + (size_t)(kv0 + rB) * 64 + ksw8, &Klds[bi][ccB * 512]);
    gload16(Vh + (size_t)rA * 1152 + kv0 + ksw8, &Vlds[bi][ccA * 512]);
    gload16(Vh + (size_t)rB * 1152 + kv0 + ksw8, &Vlds[bi][ccB * 512]);
  };

  STAGE(0, 0);
  for (int t = 0; t < 18; ++t) {
    const int kv0 = t * 64;
    const int cur = t & 1;
    __syncthreads();   // vmcnt(0) drain: stage(t) visible; prior reads done

    // mask loads first (their vmcnt wait then doesn't drain the new stage)
    f32x4 mv[4];
#pragma unroll
    for (int ni = 0; ni < 4; ++ni)
      mv[ni] = *(const f32x4*)(mrow + kv0 + ni * 16 + g * 4) * LOG2E;

    if (t + 1 < 18) STAGE(t + 1, cur ^ 1);   // overlaps compute below

    // ---- S' = (K Q^T + mask)*log2e  (scales folded; K from LDS) ----
    f32x4 st[2][4];
#pragma unroll
    for (int ni = 0; ni < 4; ++ni) {
      const unsigned short* kp = &Klds[cur][(ni * 16 + c) * 64];
      s16x8 ka0 = *(const s16x8*)(kp + q1);
      s16x8 ka1 = *(const s16x8*)(kp + q2);
#pragma unroll
      for (int mi = 0; mi < 2; ++mi) {
        f32x4 tq = __builtin_amdgcn_mfma_f32_16x16x32_bf16(ka0, qb[mi][0], fz, 0, 0, 0);
        tq = __builtin_amdgcn_mfma_f32_16x16x32_bf16(ka1, qb[mi][1], tq, 0, 0, 0);
        st[mi][ni] = tq + mv[ni];
      }
    }

    // ---- p = 2^s': raw v_exp_f32, no cross-lane ops ----
#pragma unroll
    for (int mi = 0; mi < 2; ++mi)
#pragma unroll
      for (int ni = 0; ni < 4; ++ni)
#pragma unroll
        for (int r = 0; r < 4; ++r)
          st[mi][ni][r] = vexp2(st[mi][ni][r]);

    // ---- build P^T B-fragments in-register: cvt_pk + permlane swaps ----
    s16x8 pb[2][2];
#pragma unroll
    for (int mi = 0; mi < 2; ++mi)
#pragma unroll
      for (int ks = 0; ks < 2; ++ks) {
        uint32_t x  = pk_bf16(st[mi][2 * ks][0],     st[mi][2 * ks][1]);
        uint32_t y  = pk_bf16(st[mi][2 * ks + 1][0], st[mi][2 * ks + 1][1]);
        uint32_t x2 = pk_bf16(st[mi][2 * ks][2],     st[mi][2 * ks][3]);
        uint32_t y2 = pk_bf16(st[mi][2 * ks + 1][2], st[mi][2 * ks + 1][3]);
        asm("v_permlane32_swap_b32 %0, %1" : "+v"(x), "+v"(y));
        asm("v_permlane16_swap_b32 %0, %1" : "+v"(x), "+v"(y));   // x=dw0 y=dw2
        asm("v_permlane32_swap_b32 %0, %1" : "+v"(x2), "+v"(y2));
        asm("v_permlane16_swap_b32 %0, %1" : "+v"(x2), "+v"(y2)); // x2=dw1 y2=dw3
        u32x4 dw = {x, x2, y, y2};
        pb[mi][ks] = __builtin_bit_cast(s16x8, dw);
      }

    // ---- O^T += V^T P^T ; den += ones . P^T  (V from LDS) ----
#pragma unroll
    for (int di = 0; di < 4; ++di) {
      const unsigned short* vp = &Vlds[cur][(di * 16 + c) * 64];
      s16x8 va0 = *(const s16x8*)(vp + q1);
      s16x8 va1 = *(const s16x8*)(vp + q2);
#pragma unroll
      for (int mi = 0; mi < 2; ++mi) {
        OT[mi][di] =
            __builtin_amdgcn_mfma_f32_16x16x32_bf16(va0, pb[mi][0], OT[mi][di], 0, 0, 0);
        OT[mi][di] =
            __builtin_amdgcn_mfma_f32_16x16x32_bf16(va1, pb[mi][1], OT[mi][di], 0, 0, 0);
      }
    }
#pragma unroll
    for (int mi = 0; mi < 2; ++mi) {
      den[mi] = __builtin_amdgcn_mfma_f32_16x16x32_bf16(ones, pb[mi][0], den[mi], 0, 0, 0);
      den[mi] = __builtin_amdgcn_mfma_f32_16x16x32_bf16(ones, pb[mi][1], den[mi], 0, 0, 0);
    }
  }

  // ---- normalize + direct store (block-uniform tok/ent region) ----
  float* obase;
  if (q0 < 1024) {
    obase = out + ((size_t)(b * 1024 + q0) * 1024 + h * 64);
  } else {
    obase = out + 8388608u + ((size_t)(b * 128 + (q0 - 1024)) * 1024 + h * 64);
  }
  float inv[2] = {1.0f / den[0][0], 1.0f / den[1][0]};
#pragma unroll
  for (int mi = 0; mi < 2; ++mi)
#pragma unroll
    for (int di = 0; di < 4; ++di) {
      f32x4 v = OT[mi][di] * inv[mi];
      *(f32x4*)(obase + (size_t)(mi * 16 + c) * 1024 + di * 16 + g * 4) = v;
    }
}

// ---------------- launch ----------------
extern "C" void kernel_launch(void* const* d_in, const int* in_sizes, int n_in,
                              void* d_out, int out_size, void* d_ws, size_t ws_size,
                              hipStream_t stream) {
  const float* tok  = (const float*)d_in[0];
  const float* ent  = (const float*)d_in[1];
  const float* mask = (const float*)d_in[2];
  const float* qpos = (const float*)d_in[3];
  const float* Wq  = (const float*)d_in[4];  const float* bq  = (const float*)d_in[5];
  const float* Wk  = (const float*)d_in[6];  const float* bk  = (const float*)d_in[7];
  const float* Wv  = (const float*)d_in[8];  const float* bv  = (const float*)d_in[9];
  const float* Weq = (const float*)d_in[10]; const float* beq = (const float*)d_in[11];
  const float* Wek = (const float*)d_in[12]; const float* bek = (const float*)d_in[13];
  const float* Wev = (const float*)d_in[14]; const float* bev = (const float*)d_in[15];
  float* out = (float*)d_out;

  unsigned short* ws = (unsigned short*)d_ws;
  unsigned short* tokBF = ws;
  unsigned short* peBF  = ws + 8388608;
  unsigned short* entBF = ws + 9437184;
  unsigned short* WBF   = ws + 10485760;
  unsigned short* Qb    = ws + 16777216;
  unsigned short* Kb    = ws + 26214400;
  unsigned short* Vtb   = ws + 35651584;

  prep_kernel<<<2048, 256, 0, stream>>>(tok, ent, qpos, Wq, Wk, Wv, Weq, Wek, Wev, ws);
  proj_gemm<<<dim3(24, 72), 256, 0, stream>>>(tokBF, peBF, entBF, WBF,
                                              bq, bk, bv, beq, bek, bev,
                                              Qb, Kb, Vtb);
  attn_kernel<<<1152, 256, 0, stream>>>(Qb, Kb, Vtb, mask, out);
}